// Round 5
// baseline (443.442 us; speedup 1.0000x reference)
//
#include <hip/hip_runtime.h>
#include <math.h>

#define NPAIR   131072          // 8192 freqs x 16 channels
#define STEPS   19
#define ALPHA_F 2000.0

// ================= in-LDS 8192-point radix-2 Stockham FFT =================
// 1024 threads, in-place in a single 64 KB buffer. sgn=-1 fwd, +1 inv (no 1/N).
__device__ __forceinline__ void lds_fft8192(float2* lds, int tid, float sgn) {
    for (int pass = 0; pass < 13; pass++) {
        int s = 1 << pass;
        float nf = (float)(8192 >> pass);
        float2 a[4], b[4];
        #pragma unroll
        for (int w = 0; w < 4; w++) {
            int idx = w * 1024 + tid;
            a[w] = lds[idx];
            b[w] = lds[idx + 4096];
        }
        __syncthreads();
        #pragma unroll
        for (int w = 0; w < 4; w++) {
            int idx = w * 1024 + tid;
            int q = idx & (s - 1);
            int p = idx >> pass;
            float sn, cs;
            sincospif(sgn * (float)(2 * p) / nf, &sn, &cs);   // e^{i*sgn*2pi*p/n}
            float2 av = a[w], bv = b[w];
            float2 t = make_float2(av.x - bv.x, av.y - bv.y);
            int o = 2 * idx - q;
            lds[o]     = make_float2(av.x + bv.x, av.y + bv.y);
            lds[o + s] = make_float2(t.x * cs - t.y * sn, t.x * sn + t.y * cs);
        }
        __syncthreads();
    }
}

// ================= stage A: mirror-extend + FFT16384 (split radix) -> FPT =================
__global__ __launch_bounds__(1024) void k_stageA(const float* __restrict__ sig,
                                                 float2* __restrict__ FPT) {
    extern __shared__ float2 lds[];
    int tid = threadIdx.x;
    int cw  = blockIdx.x;
    int cs  = (cw + 8) & 15;                 // fftshift over channel axis
    const float* sp = sig + cs * 8192;
    float2 regA[8];
    #pragma unroll
    for (int r = 0; r < 8; r++) {            // even samples of mirrored extension
        int p = r * 1024 + tid;
        int x = 2 * p;
        int mx = (x < 4096) ? (4095 - x) : ((x < 12288) ? (x - 4096) : (20479 - x));
        lds[p] = make_float2(sp[mx], 0.f);
    }
    __syncthreads();
    lds_fft8192(lds, tid, -1.f);
    #pragma unroll
    for (int r = 0; r < 8; r++) regA[r] = lds[r * 1024 + tid];
    __syncthreads();
    #pragma unroll
    for (int r = 0; r < 8; r++) {            // odd samples
        int p = r * 1024 + tid;
        int x = 2 * p + 1;
        int mx = (x < 4096) ? (4095 - x) : ((x < 12288) ? (x - 4096) : (20479 - x));
        lds[p] = make_float2(sp[mx], 0.f);
    }
    __syncthreads();
    lds_fft8192(lds, tid, -1.f);
    #pragma unroll
    for (int q = 0; q < 8; q++) {            // bins j=0..8191 (upper shifted half)
        int j = q * 1024 + tid;
        float2 B = lds[j];
        float sn, cn;
        sincospif(-(float)j / 8192.0f, &sn, &cn);     // e^{-2pi i j/16384}
        FPT[cw * 8192 + j] = make_float2(regA[q].x + B.x * cn - B.y * sn,
                                         regA[q].y + B.x * sn + B.y * cn);
    }
}

// ================= stage B: one VMD step (f64 math, f32 u storage) =================
__global__ void k_vmd(const float2* __restrict__ FPT, float2* __restrict__ U,
                      const double* __restrict__ nd_prev, double* __restrict__ nd_cur,
                      int step) {
    int tid = blockIdx.x * blockDim.x + threadIdx.x;  // [0,NPAIR), tid = cw*8192+j
    int j = tid & 8191;
    double fr = (double)j / 16384.0;
    float2 fv = FPT[tid];
    double fx = fv.x, fy = fv.y;
    double om[8], ux[8], uy[8];
    if (step == 0) {
        #pragma unroll
        for (int k = 0; k < 8; k++) { om[k] = 0.0625 * (double)k; ux[k] = 0.0; uy[k] = 0.0; }
    } else {
        #pragma unroll
        for (int k = 0; k < 8; k++) {
            om[k] = nd_prev[k] / nd_prev[8 + k];
            float2 u = U[k * NPAIR + tid];
            ux[k] = u.x; uy[k] = u.y;
        }
    }
    double sx = 0.0, sy = 0.0;
    #pragma unroll
    for (int k = 1; k < 8; k++) { sx += ux[k]; sy += uy[k]; }
    double lx = 0.0, ly = 0.0, nloc[8], dloc[8];
    #pragma unroll
    for (int k = 0; k < 8; k++) {
        if (k > 0) { sx += lx - ux[k]; sy += ly - uy[k]; }
        double d = fr - om[k];
        double den = 1.0 + ALPHA_F * d * d;
        double nx = (fx - sx) / den, ny = (fy - sy) / den;
        U[k * NPAIR + tid] = make_float2((float)nx, (float)ny);
        lx = nx; ly = ny;
        double pw = nx * nx + ny * ny;
        nloc[k] = fr * pw; dloc[k] = pw;
    }
    #pragma unroll
    for (int k = 0; k < 8; k++) {
        double a = nloc[k], b = dloc[k];
        for (int off = 32; off > 0; off >>= 1) {
            a += __shfl_down(a, off);
            b += __shfl_down(b, off);
        }
        nloc[k] = a; dloc[k] = b;
    }
    __shared__ double lred[4][16];
    int lane = threadIdx.x & 63, wv = threadIdx.x >> 6;
    if (lane == 0) {
        #pragma unroll
        for (int k = 0; k < 8; k++) { lred[wv][k] = nloc[k]; lred[wv][8 + k] = dloc[k]; }
    }
    __syncthreads();
    if (threadIdx.x < 16) {
        double sum = lred[0][threadIdx.x] + lred[1][threadIdx.x]
                   + lred[2][threadIdx.x] + lred[3][threadIdx.x];
        atomicAdd(&nd_cur[threadIdx.x], sum);
    }
}

// ================= stage C+D fused: hermitian iFFT16384 -> slice -> FFT8192 =================
// out0[k,t,ch] = y (f32); out1 flat = Re(u_hat2)[t,k,cw] at 1048576 + t*128 + b.
__global__ __launch_bounds__(1024) void k_stageCD(const float2* __restrict__ U,
                                                  float* __restrict__ out, int out_sz) {
    extern __shared__ float2 lds[];
    int tid = threadIdx.x;
    int b = blockIdx.x;                      // b = k*16 + cw
    int k = b >> 4, cw = b & 15;
    const float2* pos = U + b * 8192;
    const float inv = 1.0f / 16384.0f;
    float2 regA[8];
    #pragma unroll
    for (int r = 0; r < 8; r++) {            // v_even[p] = v[2p] (hermitian map)
        int p = r * 1024 + tid;
        int m = 2 * p;
        int j; bool cj;
        if (m == 0)          { j = 0;         cj = true;  }
        else if (m <= 8191)  { j = m;         cj = false; }
        else if (m == 8192)  { j = 8191;      cj = true;  }
        else                 { j = 16384 - m; cj = true;  }
        float2 pv = pos[j];
        lds[p] = make_float2(pv.x, cj ? -pv.y : pv.y);
    }
    __syncthreads();
    lds_fft8192(lds, tid, +1.f);
    #pragma unroll
    for (int r = 0; r < 8; r++) regA[r] = lds[r * 1024 + tid];
    __syncthreads();
    #pragma unroll
    for (int r = 0; r < 8; r++) {            // v_odd[p] = v[2p+1]
        int p = r * 1024 + tid;
        int m = 2 * p + 1;
        int j; bool cj;
        if (m <= 8191) { j = m;         cj = false; }
        else           { j = 16384 - m; cj = true;  }
        float2 pv = pos[j];
        lds[p] = make_float2(pv.x, cj ? -pv.y : pv.y);
    }
    __syncthreads();
    lds_fft8192(lds, tid, +1.f);
    // combine -> y[t], write out0, park y in regs
    float yreg[8];
    int ch = (cw + 8) & 15;                  // ifftshift over channel axis (u_out only)
    #pragma unroll
    for (int q = 0; q < 8; q++) {
        int t = q * 1024 + tid;
        int i = 4096 + t;
        int r = (q + 4) & 7;                 // i mod 8192 in 1024-blocks
        float2 A = regA[r];
        float2 B = lds[r * 1024 + tid];
        float sn, cn;
        sincospif((float)i / 8192.0f, &sn, &cn);   // e^{+2pi i i/16384}
        float yv = (A.x + B.x * cn - B.y * sn) * inv;
        yreg[q] = yv;
        int oidx = (k * 8192 + t) * 16 + ch;
        if (oidx < out_sz) out[oidx] = yv;
    }
    __syncthreads();
    #pragma unroll
    for (int q = 0; q < 8; q++) lds[q * 1024 + tid] = make_float2(yreg[q], 0.f);
    __syncthreads();
    lds_fft8192(lds, tid, -1.f);             // forward FFT 8192 of y
    // out1 = Re(u_hat2)[t,k,cw] = Re(Y[(t+4096) mod 8192])   (conj drops in Re)
    #pragma unroll
    for (int q = 0; q < 8; q++) {
        int t = q * 1024 + tid;
        float2 Y = lds[((q + 4) & 7) * 1024 + tid];
        int fidx = 1048576 + t * 128 + b;
        if (fidx < out_sz) out[fidx] = Y.x;
    }
}

// ================= omega history: out2 = Re(omega), 160 floats =================
__global__ void k_omega(const double* __restrict__ nd, float* __restrict__ out, int out_sz) {
    int t = threadIdx.x;
    if (t >= 160) return;
    int row = t >> 3, k = t & 7;
    double v = (row == 0) ? 0.0625 * (double)k
                          : nd[(row - 1) * 16 + k] / nd[(row - 1) * 16 + 8 + k];
    int fidx = 2097152 + t;
    if (fidx < out_sz) out[fidx] = (float)v;
}

__global__ void k_zerond(double* __restrict__ q, int n) {
    int i = blockIdx.x * blockDim.x + threadIdx.x;
    if (i < n) q[i] = 0.0;
}

extern "C" void kernel_launch(void* const* d_in, const int* in_sizes, int n_in,
                              void* d_out, int out_size, void* d_ws, size_t ws_size,
                              hipStream_t stream) {
    const float* sig = (const float*)d_in[0];
    float* out = (float*)d_out;
    char* p = (char*)d_ws;
    // ws: U 8 MB | FPT 1 MB | ND 304 doubles  (~9.01 MB total)
    float2* U   = (float2*)p;
    float2* FPT = (float2*)(p + (size_t)8 * 1024 * 1024);
    double* ND  = (double*)(p + (size_t)9 * 1024 * 1024);

    k_zerond<<<dim3(2), dim3(256), 0, stream>>>(ND, STEPS * 16);
    k_stageA<<<dim3(16), dim3(1024), 65536, stream>>>(sig, FPT);
    for (int s = 0; s < STEPS; s++) {
        const double* ndp = ND + (s > 0 ? (s - 1) * 16 : 0);
        k_vmd<<<dim3(512), dim3(256), 0, stream>>>(FPT, U, ndp, ND + s * 16, s);
    }
    k_stageCD<<<dim3(128), dim3(1024), 65536, stream>>>(U, out, out_size);
    k_omega<<<dim3(1), dim3(256), 0, stream>>>(ND, out, out_size);
}